// Round 3
// baseline (467.268 us; speedup 1.0000x reference)
//
#include <hip/hip_runtime.h>
#include <hip/hip_bf16.h>

// B=8, R=8, N=1024, D_IN=D_OUT=256, all fp32 in/out.
// prep_w : Wt[r][e][d] = bf16(W[r][d][e])         (scratch: first 1 MB of d_out, pre-memset)
// stage 1: sup[b,r,e,n] = bf16(x@W + bias)         (ws, 32 MB)
// stage 2: out[b,m,e] += adj[b,r,m,n]*sup[b,r,e,n]  (bf16 MFMA, split-K=8, atomicAdd)
// stage 3: ReLU in place.
//
// R8: R2 counters showed gcn_gemm latency-bound (Mfma 7.8%, VALU 9%, HBM 16%, occ 40%):
// __syncthreads drains vmcnt(0) at every K-iter -> prefetch slack capped at ~1 iter and the
// CU repeatedly sits with ZERO loads in flight (convoy). Rebuilt both MFMA kernels on raw
// s_barrier + counted s_waitcnt vmcnt(N) (T3/T4): adj/x register prefetch 2 iters ahead
// (2 static banks), sup/Wt DMA 2 iters ahead into 4 LDS buffers (issue at t targets buffer
// last read at t-2, already barrier-published-safe). Steady-state wait vmcnt(12) (leaves
// next 2 iters' loads flying); tail 12/12/6/0. lgkmcnt(0) before each barrier publishes
// ds_writes; sched_barrier+memory fences pin ordering; setprio around MFMA cluster (T5).
// LDS 52KB -> 3 blocks/CU (traded 1 block of occupancy for >=2-iter latency slack).

#define Rr 8
#define Nn 1024
#define Dd 256
#define PITCH 40
#define BP 32

typedef __attribute__((ext_vector_type(8))) short short8;
typedef __attribute__((ext_vector_type(4))) float f32x4;

__device__ __forceinline__ short f2bf(float f) {
    unsigned u = __builtin_bit_cast(unsigned, f);
    u += 0x7fffu + ((u >> 16) & 1u);   // RNE
    return (short)(u >> 16);
}

__device__ __forceinline__ void dma16(const void* g, void* l) {
    __builtin_amdgcn_global_load_lds(
        (const __attribute__((address_space(1))) unsigned*)g,
        (__attribute__((address_space(3))) unsigned*)l, 16, 0, 0);
}

// ---------------- prep: Wt[r][e][d] bf16 <- W[r][d][e] f32 ----------------
__global__ void prep_w_kernel(const float* __restrict__ W, short* __restrict__ Wt) {
    __shared__ short T[64][72];
    const int tid = threadIdx.x;
    const int et = blockIdx.x, dt = blockIdx.y, r = blockIdx.z;
    const float* Wr = W + ((size_t)r * Dd + dt * 64) * Dd + et * 64;
    #pragma unroll
    for (int i = 0; i < 4; ++i) {
        int idx = tid + i * 256;
        int d_l = idx >> 4;
        int e4  = (idx & 15) * 4;
        f32x4 v = *(const f32x4*)(Wr + d_l * Dd + e4);
        T[e4 + 0][d_l] = f2bf(v[0]);
        T[e4 + 1][d_l] = f2bf(v[1]);
        T[e4 + 2][d_l] = f2bf(v[2]);
        T[e4 + 3][d_l] = f2bf(v[3]);
    }
    __syncthreads();
    short* o = Wt + ((size_t)r * Dd + et * 64) * Dd + dt * 64;
    #pragma unroll
    for (int i = 0; i < 2; ++i) {
        int idx = tid + i * 256;
        *(short8*)(o + (idx >> 3) * Dd + (idx & 7) * 8) = *(const short8*)&T[idx >> 3][(idx & 7) * 8];
    }
}

// ---------------- Stage 1: sup[b,r,e,n] = bf16(Wt @ x^T + bias) ----------------
// grid (2 e_t, 8 n_t, 64 br), block 256 = 4 waves (2e x 2n), tile 128e x 128n, BK=32, 8 iters.
// A = Wt (bf16): DMA'd 2-ahead into As[4], swizzled-linear.  B = x (fp32): reg 2-bank + cvt.
__global__ __launch_bounds__(256, 3) void support_kernel(
        const float* __restrict__ x, const short* __restrict__ Wt,
        const float* __restrict__ bias, short* __restrict__ sup) {
    __shared__ short As[4][128 * BP];      // [e][d] bf16, linear, source-swizzled (32 KB)
    __shared__ short Bs[2][128 * PITCH];   // [n][d] bf16, cvt from fp32 x (20 KB)

    const int tid = threadIdx.x;
    const int wave = tid >> 6, lane = tid & 63;
    const int quad = lane >> 4, l16 = lane & 15;
    const int e_t = blockIdx.x, n_t = blockIdx.y, br = blockIdx.z;
    const int b = br >> 3, r = br & 7;
    const int we = wave & 1, wn = wave >> 1;

    const short* wp = Wt + ((size_t)r * Dd + e_t * 128) * Dd;
    const float* xb = x + ((size_t)b * Nn + n_t * 128) * Dd;

    const int drow = wave * 32 + (lane >> 2);
    const int lc   = ((lane & 3) ^ ((lane >> 3) & 3)) * 8;   // shorts
    const int bsw  = (l16 >> 1) & 3;

    f32x4 xv0[4], xv1[4];

#define GLOADX(bank, d0) do {                                                   \
        _Pragma("unroll")                                                       \
        for (int i_ = 0; i_ < 2; ++i_) {                                        \
            int idx_ = tid + i_ * 256;                                          \
            const float* p_ = xb + (idx_ >> 2) * Dd + (d0) + (idx_ & 3) * 8;    \
            bank[2 * i_]     = *(const f32x4*)p_;                               \
            bank[2 * i_ + 1] = *(const f32x4*)(p_ + 4);                         \
        }                                                                       \
    } while (0)

#define DMAW(bufi, d0) do {                                                     \
        _Pragma("unroll")                                                       \
        for (int is_ = 0; is_ < 2; ++is_) {                                     \
            const short* g_ = wp + (size_t)(drow + is_ * 16) * Dd + (d0) + lc;  \
            dma16(g_, (void*)&As[bufi][(wave * 32 + is_ * 16) * BP]);           \
        }                                                                       \
    } while (0)

#define STAGEX(bufi, bank) do {                                                 \
        _Pragma("unroll")                                                       \
        for (int i_ = 0; i_ < 2; ++i_) {                                        \
            int idx_ = tid + i_ * 256;                                          \
            short8 t_;                                                          \
            t_[0] = f2bf(bank[2 * i_][0]); t_[1] = f2bf(bank[2 * i_][1]);       \
            t_[2] = f2bf(bank[2 * i_][2]); t_[3] = f2bf(bank[2 * i_][3]);       \
            t_[4] = f2bf(bank[2 * i_ + 1][0]); t_[5] = f2bf(bank[2 * i_ + 1][1]);\
            t_[6] = f2bf(bank[2 * i_ + 1][2]); t_[7] = f2bf(bank[2 * i_ + 1][3]);\
            *(short8*)&Bs[bufi][(idx_ >> 2) * PITCH + (idx_ & 3) * 8] = t_;     \
        }                                                                       \
    } while (0)

#define ITER_S(t, bufB, bank, bufA, VM) do {                                    \
        STAGEX(bufB, bank);                                                     \
        if ((t) + 2 < 8) { GLOADX(bank, ((t) + 2) * 32); DMAW(((t) + 2) & 3, ((t) + 2) * 32); } \
        asm volatile("s_waitcnt lgkmcnt(0)" ::: "memory");                      \
        asm volatile("s_waitcnt vmcnt(" #VM ")" ::: "memory");                  \
        __builtin_amdgcn_sched_barrier(0);                                      \
        __builtin_amdgcn_s_barrier();                                           \
        asm volatile("" ::: "memory");                                          \
        short8 a_[4], bf_[4];                                                   \
        _Pragma("unroll")                                                       \
        for (int i_ = 0; i_ < 4; ++i_)                                          \
            a_[i_] = *(const short8*)&As[bufA][(we * 64 + i_ * 16 + l16) * BP + (quad ^ bsw) * 8]; \
        _Pragma("unroll")                                                       \
        for (int j_ = 0; j_ < 4; ++j_)                                          \
            bf_[j_] = *(const short8*)&Bs[bufB][(wn * 64 + j_ * 16 + l16) * PITCH + quad * 8]; \
        __builtin_amdgcn_s_setprio(1);                                          \
        _Pragma("unroll")                                                       \
        for (int i_ = 0; i_ < 4; ++i_)                                          \
            _Pragma("unroll")                                                   \
            for (int j_ = 0; j_ < 4; ++j_)                                      \
                acc[i_][j_] = __builtin_amdgcn_mfma_f32_16x16x32_bf16(a_[i_], bf_[j_], acc[i_][j_], 0, 0, 0); \
        __builtin_amdgcn_s_setprio(0);                                          \
    } while (0)

    f32x4 acc[4][4] = {};
    // prologue (FIFO order: gX(0), dma(0), gX(1), dma(1))
    GLOADX(xv0, 0); DMAW(0, 0);
    GLOADX(xv1, 32); DMAW(1, 32);
    ITER_S(0, 0, xv0, 0, 12);
    ITER_S(1, 1, xv1, 1, 12);
    ITER_S(2, 0, xv0, 2, 12);
    ITER_S(3, 1, xv1, 3, 12);
    ITER_S(4, 0, xv0, 0, 12);
    ITER_S(5, 1, xv1, 1, 12);
    ITER_S(6, 0, xv0, 2, 6);
    ITER_S(7, 1, xv1, 3, 0);
#undef GLOADX
#undef DMAW
#undef STAGEX
#undef ITER_S

    // Epilogue: C[row=e][col=n]; add bias; bf16 store to sup[(b,r),e,n].
    #pragma unroll
    for (int i = 0; i < 4; ++i)
        #pragma unroll
        for (int reg = 0; reg < 4; ++reg) {
            int e = e_t * 128 + we * 64 + i * 16 + quad * 4 + reg;
            float bv = bias[r * Dd + e];
            #pragma unroll
            for (int j = 0; j < 4; ++j) {
                int n = n_t * 128 + wn * 64 + j * 16 + l16;
                sup[(((b * Rr + r) * Dd + e) << 10) + n] = f2bf(acc[i][j][reg] + bv);
            }
        }
}

// ---------------- Stage 2: out += adj @ sup^T (split-K=8) ----------------
// grid (16, 8, 8); bx: r = bx&7, e2 = bx>>3 -> e2-pairs differ by 8 -> same XCD (L2-share adj).
// block 256 = 4 waves (2m x 2e), tile 128m x 128e, BK=32, 32 iters.
// A = adj (fp32): reg 2-bank + cvt, PITCH 40.  B = sup (bf16): DMA'd 2-ahead into Bs[4].
__global__ __launch_bounds__(256, 3) void gcn_gemm_kernel(
        const float* __restrict__ adj, const short* __restrict__ sup,
        float* __restrict__ out) {
    __shared__ short Aa[2][128 * PITCH];   // [m][k] bf16 (cvt from fp32 adj), 20 KB
    __shared__ short Bs[4][128 * BP];      // [e][k] bf16, linear, source-swizzled, 32 KB

    const int tid = threadIdx.x;
    const int wave = tid >> 6, lane = tid & 63;
    const int quad = lane >> 4, l16 = lane & 15;
    const int r = blockIdx.x & 7, e2 = blockIdx.x >> 3;
    const int m_t = blockIdx.y, b = blockIdx.z;
    const int wm = wave >> 1, we = wave & 1;

    const float* ap = adj + ((size_t)((b * Rr + r) * Nn + m_t * 128)) * Nn;
    const short* bp = sup + (((size_t)((b * Rr + r) * Dd + e2 * 128)) << 10);

    const int drow = wave * 32 + (lane >> 2);
    const int lc   = ((lane & 3) ^ ((lane >> 3) & 3)) * 8;   // shorts
    const int bsw  = (l16 >> 1) & 3;

    f32x4 av0[4], av1[4];

#define GLOADA(bank, kk) do {                                                   \
        _Pragma("unroll")                                                       \
        for (int i_ = 0; i_ < 2; ++i_) {                                        \
            int idx_ = tid + i_ * 256;                                          \
            const float* p_ = ap + (size_t)(idx_ >> 2) * Nn + (kk) + (idx_ & 3) * 8; \
            bank[2 * i_]     = *(const f32x4*)p_;                               \
            bank[2 * i_ + 1] = *(const f32x4*)(p_ + 4);                         \
        }                                                                       \
    } while (0)

#define DMAB(bufi, kk) do {                                                     \
        _Pragma("unroll")                                                       \
        for (int is_ = 0; is_ < 2; ++is_) {                                     \
            const short* g_ = bp + ((size_t)(drow + is_ * 16) << 10) + (kk) + lc; \
            dma16(g_, (void*)&Bs[bufi][(wave * 32 + is_ * 16) * BP]);           \
        }                                                                       \
    } while (0)

#define STAGEA(bufi, bank) do {                                                 \
        _Pragma("unroll")                                                       \
        for (int i_ = 0; i_ < 2; ++i_) {                                        \
            int idx_ = tid + i_ * 256;                                          \
            short8 t_;                                                          \
            t_[0] = f2bf(bank[2 * i_][0]); t_[1] = f2bf(bank[2 * i_][1]);       \
            t_[2] = f2bf(bank[2 * i_][2]); t_[3] = f2bf(bank[2 * i_][3]);       \
            t_[4] = f2bf(bank[2 * i_ + 1][0]); t_[5] = f2bf(bank[2 * i_ + 1][1]);\
            t_[6] = f2bf(bank[2 * i_ + 1][2]); t_[7] = f2bf(bank[2 * i_ + 1][3]);\
            *(short8*)&Aa[bufi][(idx_ >> 2) * PITCH + (idx_ & 3) * 8] = t_;     \
        }                                                                       \
    } while (0)

#define ITER_G(t, bufA, bank, bufB, VM) do {                                    \
        STAGEA(bufA, bank);                                                     \
        if ((t) + 2 < 32) { GLOADA(bank, ((t) + 2) * 32); DMAB(((t) + 2) & 3, ((t) + 2) * 32); } \
        asm volatile("s_waitcnt lgkmcnt(0)" ::: "memory");                      \
        asm volatile("s_waitcnt vmcnt(" #VM ")" ::: "memory");                  \
        __builtin_amdgcn_sched_barrier(0);                                      \
        __builtin_amdgcn_s_barrier();                                           \
        asm volatile("" ::: "memory");                                          \
        short8 a_[4], bf_[4];                                                   \
        _Pragma("unroll")                                                       \
        for (int i_ = 0; i_ < 4; ++i_)                                          \
            a_[i_] = *(const short8*)&Aa[bufA][(wm * 64 + i_ * 16 + l16) * PITCH + quad * 8]; \
        _Pragma("unroll")                                                       \
        for (int j_ = 0; j_ < 4; ++j_)                                          \
            bf_[j_] = *(const short8*)&Bs[bufB][(we * 64 + j_ * 16 + l16) * BP + (quad ^ bsw) * 8]; \
        __builtin_amdgcn_s_setprio(1);                                          \
        _Pragma("unroll")                                                       \
        for (int i_ = 0; i_ < 4; ++i_)                                          \
            _Pragma("unroll")                                                   \
            for (int j_ = 0; j_ < 4; ++j_)                                      \
                acc[i_][j_] = __builtin_amdgcn_mfma_f32_16x16x32_bf16(a_[i_], bf_[j_], acc[i_][j_], 0, 0, 0); \
        __builtin_amdgcn_s_setprio(0);                                          \
    } while (0)

    f32x4 acc[4][4] = {};
    // prologue (FIFO order: gA(0), dma(0), gA(1), dma(1))
    GLOADA(av0, 0); DMAB(0, 0);
    GLOADA(av1, 32); DMAB(1, 32);
    // main: t = 0..27, bufB cycles 0..3 (t0 multiple of 4), steady vmcnt(12)
    for (int t0 = 0; t0 < 28; t0 += 4) {
        ITER_G(t0 + 0, 0, av0, 0, 12);
        ITER_G(t0 + 1, 1, av1, 1, 12);
        ITER_G(t0 + 2, 0, av0, 2, 12);
        ITER_G(t0 + 3, 1, av1, 3, 12);
    }
    // tail: t = 28..31 (28,29 still issue t+2; 30,31 drain)
    ITER_G(28, 0, av0, 0, 12);
    ITER_G(29, 1, av1, 1, 12);
    ITER_G(30, 0, av0, 2, 6);
    ITER_G(31, 1, av1, 3, 0);
#undef GLOADA
#undef DMAB
#undef STAGEA
#undef ITER_G

    // Epilogue: C[row=m][col=e]; split-K partial -> atomicAdd into zeroed out.
    float* ob = out + ((size_t)b * Nn + m_t * 128) * Dd + e2 * 128;
    #pragma unroll
    for (int i = 0; i < 4; ++i)
        #pragma unroll
        for (int reg = 0; reg < 4; ++reg) {
            int m_l = wm * 64 + i * 16 + quad * 4 + reg;
            #pragma unroll
            for (int j = 0; j < 4; ++j)
                atomicAdd(ob + (size_t)m_l * Dd + we * 64 + j * 16 + l16, acc[i][j][reg]);
        }
}

// ---------------- Stage 3: ReLU in place ----------------
__global__ void relu_kernel(float* __restrict__ out, int n4) {
    int i = blockIdx.x * blockDim.x + threadIdx.x;
    if (i < n4) {
        f32x4* p = (f32x4*)out;
        f32x4 v = p[i];
        v[0] = fmaxf(v[0], 0.f); v[1] = fmaxf(v[1], 0.f);
        v[2] = fmaxf(v[2], 0.f); v[3] = fmaxf(v[3], 0.f);
        p[i] = v;
    }
}

extern "C" void kernel_launch(void* const* d_in, const int* in_sizes, int n_in,
                              void* d_out, int out_size, void* d_ws, size_t ws_size,
                              hipStream_t stream) {
    const float* x    = (const float*)d_in[0];
    const float* adj  = (const float*)d_in[1];
    const float* W    = (const float*)d_in[2];
    const float* bias = (const float*)d_in[3];
    float* out = (float*)d_out;
    short* sup = (short*)d_ws;            // 32 MB of ws
    short* Wt  = (short*)d_out;           // 1 MB scratch inside d_out, consumed before memset

    prep_w_kernel<<<dim3(4, 4, 8), 256, 0, stream>>>(W, Wt);
    support_kernel<<<dim3(2, 8, 64), 256, 0, stream>>>(x, Wt, bias, sup);
    hipMemsetAsync(d_out, 0, (size_t)out_size * sizeof(float), stream);
    gcn_gemm_kernel<<<dim3(16, 8, 8), 256, 0, stream>>>(adj, sup, out);
    relu_kernel<<<(out_size / 4 + 255) / 256, 256, 0, stream>>>(out, out_size / 4);
}

// Round 4
// 456.649 us; speedup vs baseline: 1.0233x; 1.0233x over previous
//
#include <hip/hip_runtime.h>
#include <hip/hip_bf16.h>

// B=8, R=8, N=1024, D_IN=D_OUT=256, all fp32 in/out.
// prep_w : Wt[r][e][d] = bf16(W[r][d][e])          (scratch: first 1 MB of d_out)
// stage 1: sup[b,r,e,n] = bf16(x@W + bias)          (ws[0:32MB])
// stage 2: part[r][b][m][e] = adj[b,r,m,:]@sup[b,r,:,e]  (bf16 MFMA, plain stores, ws[32:96MB])
// stage 3: out = relu(sum_r part[r]) fused reduce.
//
// R8: counted-vmcnt 2-deep pipeline (T3/T4) in both MFMA kernels. NEUTRAL vs R2's
// syncthreads version (167us invariant) -> K-loop is not the binding constraint.
//
// R9: the invariant was the split-K atomic epilogue: 16.8M device-scope f32 atomicAdds;
// WRITE_SIZE=80MB for an 8MB output showed every atomic RMW'ing at the chip-wide coherence
// point (per-XCD L2s non-coherent -> device-scope adds serialize at fabric/MALL, ~100us).
// Replaced with plain fp32 partial stores (64MB in ws) + fused reduce_relu kernel
// (64MB read + 8MB write ~ 13us streaming). memset + separate relu kernels deleted.

#define Rr 8
#define Nn 1024
#define Dd 256
#define PITCH 40
#define BP 32

typedef __attribute__((ext_vector_type(8))) short short8;
typedef __attribute__((ext_vector_type(4))) float f32x4;

__device__ __forceinline__ short f2bf(float f) {
    unsigned u = __builtin_bit_cast(unsigned, f);
    u += 0x7fffu + ((u >> 16) & 1u);   // RNE
    return (short)(u >> 16);
}

__device__ __forceinline__ void dma16(const void* g, void* l) {
    __builtin_amdgcn_global_load_lds(
        (const __attribute__((address_space(1))) unsigned*)g,
        (__attribute__((address_space(3))) unsigned*)l, 16, 0, 0);
}

// ---------------- prep: Wt[r][e][d] bf16 <- W[r][d][e] f32 ----------------
__global__ void prep_w_kernel(const float* __restrict__ W, short* __restrict__ Wt) {
    __shared__ short T[64][72];
    const int tid = threadIdx.x;
    const int et = blockIdx.x, dt = blockIdx.y, r = blockIdx.z;
    const float* Wr = W + ((size_t)r * Dd + dt * 64) * Dd + et * 64;
    #pragma unroll
    for (int i = 0; i < 4; ++i) {
        int idx = tid + i * 256;
        int d_l = idx >> 4;
        int e4  = (idx & 15) * 4;
        f32x4 v = *(const f32x4*)(Wr + d_l * Dd + e4);
        T[e4 + 0][d_l] = f2bf(v[0]);
        T[e4 + 1][d_l] = f2bf(v[1]);
        T[e4 + 2][d_l] = f2bf(v[2]);
        T[e4 + 3][d_l] = f2bf(v[3]);
    }
    __syncthreads();
    short* o = Wt + ((size_t)r * Dd + et * 64) * Dd + dt * 64;
    #pragma unroll
    for (int i = 0; i < 2; ++i) {
        int idx = tid + i * 256;
        *(short8*)(o + (idx >> 3) * Dd + (idx & 7) * 8) = *(const short8*)&T[idx >> 3][(idx & 7) * 8];
    }
}

// ---------------- Stage 1: sup[b,r,e,n] = bf16(Wt @ x^T + bias) ----------------
// grid (2 e_t, 8 n_t, 64 br), block 256 = 4 waves (2e x 2n), tile 128e x 128n, BK=32, 8 iters.
// A = Wt (bf16): DMA'd 2-ahead into As[4], swizzled-linear.  B = x (fp32): reg 2-bank + cvt.
__global__ __launch_bounds__(256, 3) void support_kernel(
        const float* __restrict__ x, const short* __restrict__ Wt,
        const float* __restrict__ bias, short* __restrict__ sup) {
    __shared__ short As[4][128 * BP];      // [e][d] bf16, linear, source-swizzled (32 KB)
    __shared__ short Bs[2][128 * PITCH];   // [n][d] bf16, cvt from fp32 x (20 KB)

    const int tid = threadIdx.x;
    const int wave = tid >> 6, lane = tid & 63;
    const int quad = lane >> 4, l16 = lane & 15;
    const int e_t = blockIdx.x, n_t = blockIdx.y, br = blockIdx.z;
    const int b = br >> 3, r = br & 7;
    const int we = wave & 1, wn = wave >> 1;

    const short* wp = Wt + ((size_t)r * Dd + e_t * 128) * Dd;
    const float* xb = x + ((size_t)b * Nn + n_t * 128) * Dd;

    const int drow = wave * 32 + (lane >> 2);
    const int lc   = ((lane & 3) ^ ((lane >> 3) & 3)) * 8;   // shorts
    const int bsw  = (l16 >> 1) & 3;

    f32x4 xv0[4], xv1[4];

#define GLOADX(bank, d0) do {                                                   \
        _Pragma("unroll")                                                       \
        for (int i_ = 0; i_ < 2; ++i_) {                                        \
            int idx_ = tid + i_ * 256;                                          \
            const float* p_ = xb + (idx_ >> 2) * Dd + (d0) + (idx_ & 3) * 8;    \
            bank[2 * i_]     = *(const f32x4*)p_;                               \
            bank[2 * i_ + 1] = *(const f32x4*)(p_ + 4);                         \
        }                                                                       \
    } while (0)

#define DMAW(bufi, d0) do {                                                     \
        _Pragma("unroll")                                                       \
        for (int is_ = 0; is_ < 2; ++is_) {                                     \
            const short* g_ = wp + (size_t)(drow + is_ * 16) * Dd + (d0) + lc;  \
            dma16(g_, (void*)&As[bufi][(wave * 32 + is_ * 16) * BP]);           \
        }                                                                       \
    } while (0)

#define STAGEX(bufi, bank) do {                                                 \
        _Pragma("unroll")                                                       \
        for (int i_ = 0; i_ < 2; ++i_) {                                        \
            int idx_ = tid + i_ * 256;                                          \
            short8 t_;                                                          \
            t_[0] = f2bf(bank[2 * i_][0]); t_[1] = f2bf(bank[2 * i_][1]);       \
            t_[2] = f2bf(bank[2 * i_][2]); t_[3] = f2bf(bank[2 * i_][3]);       \
            t_[4] = f2bf(bank[2 * i_ + 1][0]); t_[5] = f2bf(bank[2 * i_ + 1][1]);\
            t_[6] = f2bf(bank[2 * i_ + 1][2]); t_[7] = f2bf(bank[2 * i_ + 1][3]);\
            *(short8*)&Bs[bufi][(idx_ >> 2) * PITCH + (idx_ & 3) * 8] = t_;     \
        }                                                                       \
    } while (0)

#define ITER_S(t, bufB, bank, bufA, VM) do {                                    \
        STAGEX(bufB, bank);                                                     \
        if ((t) + 2 < 8) { GLOADX(bank, ((t) + 2) * 32); DMAW(((t) + 2) & 3, ((t) + 2) * 32); } \
        asm volatile("s_waitcnt lgkmcnt(0)" ::: "memory");                      \
        asm volatile("s_waitcnt vmcnt(" #VM ")" ::: "memory");                  \
        __builtin_amdgcn_sched_barrier(0);                                      \
        __builtin_amdgcn_s_barrier();                                           \
        asm volatile("" ::: "memory");                                          \
        short8 a_[4], bf_[4];                                                   \
        _Pragma("unroll")                                                       \
        for (int i_ = 0; i_ < 4; ++i_)                                          \
            a_[i_] = *(const short8*)&As[bufA][(we * 64 + i_ * 16 + l16) * BP + (quad ^ bsw) * 8]; \
        _Pragma("unroll")                                                       \
        for (int j_ = 0; j_ < 4; ++j_)                                          \
            bf_[j_] = *(const short8*)&Bs[bufB][(wn * 64 + j_ * 16 + l16) * PITCH + quad * 8]; \
        __builtin_amdgcn_s_setprio(1);                                          \
        _Pragma("unroll")                                                       \
        for (int i_ = 0; i_ < 4; ++i_)                                          \
            _Pragma("unroll")                                                   \
            for (int j_ = 0; j_ < 4; ++j_)                                      \
                acc[i_][j_] = __builtin_amdgcn_mfma_f32_16x16x32_bf16(a_[i_], bf_[j_], acc[i_][j_], 0, 0, 0); \
        __builtin_amdgcn_s_setprio(0);                                          \
    } while (0)

    f32x4 acc[4][4] = {};
    // prologue (FIFO order: gX(0), dma(0), gX(1), dma(1))
    GLOADX(xv0, 0); DMAW(0, 0);
    GLOADX(xv1, 32); DMAW(1, 32);
    ITER_S(0, 0, xv0, 0, 12);
    ITER_S(1, 1, xv1, 1, 12);
    ITER_S(2, 0, xv0, 2, 12);
    ITER_S(3, 1, xv1, 3, 12);
    ITER_S(4, 0, xv0, 0, 12);
    ITER_S(5, 1, xv1, 1, 12);
    ITER_S(6, 0, xv0, 2, 6);
    ITER_S(7, 1, xv1, 3, 0);
#undef GLOADX
#undef DMAW
#undef STAGEX
#undef ITER_S

    // Epilogue: C[row=e][col=n]; add bias; bf16 store to sup[(b,r),e,n].
    #pragma unroll
    for (int i = 0; i < 4; ++i)
        #pragma unroll
        for (int reg = 0; reg < 4; ++reg) {
            int e = e_t * 128 + we * 64 + i * 16 + quad * 4 + reg;
            float bv = bias[r * Dd + e];
            #pragma unroll
            for (int j = 0; j < 4; ++j) {
                int n = n_t * 128 + wn * 64 + j * 16 + l16;
                sup[(((b * Rr + r) * Dd + e) << 10) + n] = f2bf(acc[i][j][reg] + bv);
            }
        }
}

// ---------------- Stage 2: part[r][b][m][e] = adj @ sup^T (split-K=8, plain stores) ----------
// grid (16, 8, 8); bx: r = bx&7, e2 = bx>>3 -> e2-pairs differ by 8 -> same XCD (L2-share adj).
// block 256 = 4 waves (2m x 2e), tile 128m x 128e, BK=32, 32 iters.
// A = adj (fp32): reg 2-bank + cvt, PITCH 40.  B = sup (bf16): DMA'd 2-ahead into Bs[4].
__global__ __launch_bounds__(256, 3) void gcn_gemm_kernel(
        const float* __restrict__ adj, const short* __restrict__ sup,
        float* __restrict__ part) {
    __shared__ short Aa[2][128 * PITCH];   // [m][k] bf16 (cvt from fp32 adj), 20 KB
    __shared__ short Bs[4][128 * BP];      // [e][k] bf16, linear, source-swizzled, 32 KB

    const int tid = threadIdx.x;
    const int wave = tid >> 6, lane = tid & 63;
    const int quad = lane >> 4, l16 = lane & 15;
    const int r = blockIdx.x & 7, e2 = blockIdx.x >> 3;
    const int m_t = blockIdx.y, b = blockIdx.z;
    const int wm = wave >> 1, we = wave & 1;

    const float* ap = adj + ((size_t)((b * Rr + r) * Nn + m_t * 128)) * Nn;
    const short* bp = sup + (((size_t)((b * Rr + r) * Dd + e2 * 128)) << 10);

    const int drow = wave * 32 + (lane >> 2);
    const int lc   = ((lane & 3) ^ ((lane >> 3) & 3)) * 8;   // shorts
    const int bsw  = (l16 >> 1) & 3;

    f32x4 av0[4], av1[4];

#define GLOADA(bank, kk) do {                                                   \
        _Pragma("unroll")                                                       \
        for (int i_ = 0; i_ < 2; ++i_) {                                        \
            int idx_ = tid + i_ * 256;                                          \
            const float* p_ = ap + (size_t)(idx_ >> 2) * Nn + (kk) + (idx_ & 3) * 8; \
            bank[2 * i_]     = *(const f32x4*)p_;                               \
            bank[2 * i_ + 1] = *(const f32x4*)(p_ + 4);                         \
        }                                                                       \
    } while (0)

#define DMAB(bufi, kk) do {                                                     \
        _Pragma("unroll")                                                       \
        for (int is_ = 0; is_ < 2; ++is_) {                                     \
            const short* g_ = bp + ((size_t)(drow + is_ * 16) << 10) + (kk) + lc; \
            dma16(g_, (void*)&Bs[bufi][(wave * 32 + is_ * 16) * BP]);           \
        }                                                                       \
    } while (0)

#define STAGEA(bufi, bank) do {                                                 \
        _Pragma("unroll")                                                       \
        for (int i_ = 0; i_ < 2; ++i_) {                                        \
            int idx_ = tid + i_ * 256;                                          \
            short8 t_;                                                          \
            t_[0] = f2bf(bank[2 * i_][0]); t_[1] = f2bf(bank[2 * i_][1]);       \
            t_[2] = f2bf(bank[2 * i_][2]); t_[3] = f2bf(bank[2 * i_][3]);       \
            t_[4] = f2bf(bank[2 * i_ + 1][0]); t_[5] = f2bf(bank[2 * i_ + 1][1]);\
            t_[6] = f2bf(bank[2 * i_ + 1][2]); t_[7] = f2bf(bank[2 * i_ + 1][3]);\
            *(short8*)&Aa[bufi][(idx_ >> 2) * PITCH + (idx_ & 3) * 8] = t_;     \
        }                                                                       \
    } while (0)

#define ITER_G(t, bufA, bank, bufB, VM) do {                                    \
        STAGEA(bufA, bank);                                                     \
        if ((t) + 2 < 32) { GLOADA(bank, ((t) + 2) * 32); DMAB(((t) + 2) & 3, ((t) + 2) * 32); } \
        asm volatile("s_waitcnt lgkmcnt(0)" ::: "memory");                      \
        asm volatile("s_waitcnt vmcnt(" #VM ")" ::: "memory");                  \
        __builtin_amdgcn_sched_barrier(0);                                      \
        __builtin_amdgcn_s_barrier();                                           \
        asm volatile("" ::: "memory");                                          \
        short8 a_[4], bf_[4];                                                   \
        _Pragma("unroll")                                                       \
        for (int i_ = 0; i_ < 4; ++i_)                                          \
            a_[i_] = *(const short8*)&Aa[bufA][(wm * 64 + i_ * 16 + l16) * PITCH + quad * 8]; \
        _Pragma("unroll")                                                       \
        for (int j_ = 0; j_ < 4; ++j_)                                          \
            bf_[j_] = *(const short8*)&Bs[bufB][(we * 64 + j_ * 16 + l16) * BP + (quad ^ bsw) * 8]; \
        __builtin_amdgcn_s_setprio(1);                                          \
        _Pragma("unroll")                                                       \
        for (int i_ = 0; i_ < 4; ++i_)                                          \
            _Pragma("unroll")                                                   \
            for (int j_ = 0; j_ < 4; ++j_)                                      \
                acc[i_][j_] = __builtin_amdgcn_mfma_f32_16x16x32_bf16(a_[i_], bf_[j_], acc[i_][j_], 0, 0, 0); \
        __builtin_amdgcn_s_setprio(0);                                          \
    } while (0)

    f32x4 acc[4][4] = {};
    // prologue (FIFO order: gA(0), dma(0), gA(1), dma(1))
    GLOADA(av0, 0); DMAB(0, 0);
    GLOADA(av1, 32); DMAB(1, 32);
    // main: t = 0..27, bufB cycles 0..3 (t0 multiple of 4), steady vmcnt(12)
    for (int t0 = 0; t0 < 28; t0 += 4) {
        ITER_G(t0 + 0, 0, av0, 0, 12);
        ITER_G(t0 + 1, 1, av1, 1, 12);
        ITER_G(t0 + 2, 0, av0, 2, 12);
        ITER_G(t0 + 3, 1, av1, 3, 12);
    }
    // tail: t = 28..31 (28,29 still issue t+2; 30,31 drain)
    ITER_G(28, 0, av0, 0, 12);
    ITER_G(29, 1, av1, 1, 12);
    ITER_G(30, 0, av0, 2, 6);
    ITER_G(31, 1, av1, 3, 0);
#undef GLOADA
#undef DMAB
#undef STAGEA
#undef ITER_G

    // Epilogue: C[row=m][col=e]; plain fp32 stores to this relation's partial slab.
    float* pr = part + ((size_t)r << 21) + ((size_t)b * Nn + m_t * 128) * Dd + e2 * 128;
    #pragma unroll
    for (int i = 0; i < 4; ++i)
        #pragma unroll
        for (int reg = 0; reg < 4; ++reg) {
            int m_l = wm * 64 + i * 16 + quad * 4 + reg;
            #pragma unroll
            for (int j = 0; j < 4; ++j)
                pr[(size_t)m_l * Dd + we * 64 + j * 16 + l16] = acc[i][j][reg];
        }
}

// ---------------- Stage 3: out = relu(sum_r part[r]) ----------------
__global__ __launch_bounds__(256) void reduce_relu_kernel(
        const float* __restrict__ part, float* __restrict__ out, int n4) {
    int i = blockIdx.x * blockDim.x + threadIdx.x;
    if (i >= n4) return;
    const f32x4* p = (const f32x4*)part;
    f32x4 v = p[i];
    #pragma unroll
    for (int k = 1; k < 8; ++k) {
        f32x4 t = p[i + ((size_t)k << 19)];   // slab stride = 2M floats = 512K f32x4
        v[0] += t[0]; v[1] += t[1]; v[2] += t[2]; v[3] += t[3];
    }
    v[0] = fmaxf(v[0], 0.f); v[1] = fmaxf(v[1], 0.f);
    v[2] = fmaxf(v[2], 0.f); v[3] = fmaxf(v[3], 0.f);
    ((f32x4*)out)[i] = v;
}

extern "C" void kernel_launch(void* const* d_in, const int* in_sizes, int n_in,
                              void* d_out, int out_size, void* d_ws, size_t ws_size,
                              hipStream_t stream) {
    const float* x    = (const float*)d_in[0];
    const float* adj  = (const float*)d_in[1];
    const float* W    = (const float*)d_in[2];
    const float* bias = (const float*)d_in[3];
    float* out = (float*)d_out;
    short* sup  = (short*)d_ws;                              // ws[0:32MB)
    float* part = (float*)((char*)d_ws + (32u << 20));       // ws[32MB:96MB), [r][b][m][e] fp32
    short* Wt   = (short*)d_out;   // 1 MB scratch inside d_out, overwritten by reduce at the end

    prep_w_kernel<<<dim3(4, 4, 8), 256, 0, stream>>>(W, Wt);
    support_kernel<<<dim3(2, 8, 64), 256, 0, stream>>>(x, Wt, bias, sup);
    gcn_gemm_kernel<<<dim3(16, 8, 8), 256, 0, stream>>>(adj, sup, part);
    reduce_relu_kernel<<<(out_size / 4 + 255) / 256, 256, 0, stream>>>(part, out, out_size / 4);
}